// Round 1
// baseline (116.665 us; speedup 1.0000x reference)
//
#include <hip/hip_runtime.h>
#include <hip/hip_bf16.h>

typedef __bf16 bf16_t;
typedef __attribute__((ext_vector_type(8))) __bf16 bf16x8;
typedef __attribute__((ext_vector_type(4))) __bf16 bf16x4;
typedef __attribute__((ext_vector_type(4))) float f32x4;

#define MFMA(a, b, c) __builtin_amdgcn_mfma_f32_16x16x32_bf16((a), (b), (c), 0, 0, 0)

static __device__ __forceinline__ bf16x8 zero_bf16x8() {
  bf16x8 z;
#pragma unroll
  for (int i = 0; i < 8; ++i) z[i] = (bf16_t)0.f;
  return z;
}

// ---------------------------------------------------------------------------
// Kernel 0: weights -> bf16, B-fragment friendly [n][k] layout.
// mats 0..2 (QTrans,KTrans,VTrans) are [k=256][n=256] row-major -> transpose.
// mats 3..4 (GW,OW) are [n=256][k=256] row-major -> straight cast.
// ---------------------------------------------------------------------------
__global__ __launch_bounds__(256) void prep_weights(
    const float* __restrict__ QT, const float* __restrict__ KT,
    const float* __restrict__ VTr, const float* __restrict__ GW,
    const float* __restrict__ OW, bf16_t* __restrict__ Wb) {
  int e = blockIdx.x * 256 + threadIdx.x;  // 0 .. 5*65536-1
  int mat = e >> 16;
  int r = e & 65535;
  const float* src = (mat == 0) ? QT : (mat == 1) ? KT : (mat == 2) ? VTr
                     : (mat == 3) ? GW : OW;
  float v = src[r];  // coalesced read
  int dst;
  if (mat < 3) {
    int k = r >> 8, n = r & 255;
    dst = n * 256 + k;  // scattered 2B write, tiny matrix, fine
  } else {
    dst = r;
  }
  Wb[mat * 65536 + dst] = (bf16_t)v;
}

// ---------------------------------------------------------------------------
// Kernel 1: projections. grid (Mtiles=64, Ntiles=4, job=4), 256 thr = 4 waves,
// each wave computes a 16(m) x 64(n) tile, K=256 in 8 chunks of 32.
// job 0: Q=Qin@QTrans -> Qb bf16 [B,S,256]
// job 1: K=Kin@KTrans -> Kb bf16 [B,S,256]
// job 2: V=Vin@VTrans -> VT bf16 [B,H,C,S] (transposed for PV B-fragments)
// job 3: G=sigmoid(Vin@GW.T+Gb) -> G bf16 [B,S,256]
// ---------------------------------------------------------------------------
__global__ __launch_bounds__(256) void proj_kernel(
    const float* __restrict__ Qin, const float* __restrict__ Kin,
    const float* __restrict__ Vin, const bf16_t* __restrict__ Wb,
    const float* __restrict__ Gb, bf16_t* __restrict__ Qb,
    bf16_t* __restrict__ Kb, bf16_t* __restrict__ VT, bf16_t* __restrict__ G) {
  const int tid = threadIdx.x, w = tid >> 6, lane = tid & 63;
  const int quad = lane >> 4, t15 = lane & 15;
  const int job = blockIdx.z;
  const int m0 = blockIdx.x * 64 + w * 16;
  const int n0 = blockIdx.y * 64;
  const float* A = (job == 0) ? Qin : (job == 1) ? Kin : Vin;
  const bf16_t* W = Wb + job * 65536;

  const f32x4 zf = {0.f, 0.f, 0.f, 0.f};
  f32x4 acc[4] = {zf, zf, zf, zf};

  for (int kc = 0; kc < 8; ++kc) {
    const float* ap = A + (size_t)(m0 + t15) * 256 + kc * 32 + quad * 8;
    float4 x0 = *(const float4*)ap;
    float4 x1 = *(const float4*)(ap + 4);
    bf16x8 a;
    a[0] = (bf16_t)x0.x; a[1] = (bf16_t)x0.y; a[2] = (bf16_t)x0.z; a[3] = (bf16_t)x0.w;
    a[4] = (bf16_t)x1.x; a[5] = (bf16_t)x1.y; a[6] = (bf16_t)x1.z; a[7] = (bf16_t)x1.w;
#pragma unroll
    for (int nf = 0; nf < 4; ++nf) {
      bf16x8 bw = *(const bf16x8*)(W + (size_t)(n0 + nf * 16 + t15) * 256 + kc * 32 + quad * 8);
      acc[nf] = MFMA(a, bw, acc[nf]);
    }
  }

  const int mm0 = m0 + quad * 4;  // 4 consecutive output rows (r=0..3)
  if (job == 2) {
    const int b = mm0 >> 11;
    const int s = mm0 & 2047;
#pragma unroll
    for (int nf = 0; nf < 4; ++nf) {
      int nn = n0 + nf * 16 + t15;
      int h = nn >> 5, c = nn & 31;
      bf16x4 v4;
#pragma unroll
      for (int r = 0; r < 4; ++r) v4[r] = (bf16_t)acc[nf][r];
      *(bf16x4*)(VT + (size_t)((b * 8 + h) * 32 + c) * 2048 + s) = v4;
    }
  } else if (job == 3) {
#pragma unroll
    for (int nf = 0; nf < 4; ++nf) {
      int nn = n0 + nf * 16 + t15;
      float bias = Gb[nn];
#pragma unroll
      for (int r = 0; r < 4; ++r) {
        float g = 1.f / (1.f + __expf(-(acc[nf][r] + bias)));
        G[(size_t)(mm0 + r) * 256 + nn] = (bf16_t)g;
      }
    }
  } else {
    bf16_t* dst = (job == 0) ? Qb : Kb;
#pragma unroll
    for (int nf = 0; nf < 4; ++nf) {
      int nn = n0 + nf * 16 + t15;
#pragma unroll
      for (int r = 0; r < 4; ++r)
        dst[(size_t)(mm0 + r) * 256 + nn] = (bf16_t)acc[nf][r];
    }
  }
}

// ---------------------------------------------------------------------------
// Kernel 2: windowed attention. One wave per (b, h, 16-query tile).
// Scores: 5 MFMAs over key span [q0-32, q0+47]; mask |q-t|<=32 & 0<=t<S;
// fp32 softmax (16-lane shuffle reduce); P -> LDS (C-layout -> A-layout);
// PV: 3 k-chunks x 2 c-halves MFMAs; multiply by G; store O bf16 [B,S,256].
// ---------------------------------------------------------------------------
__global__ __launch_bounds__(256) void attn_kernel(
    const bf16_t* __restrict__ Qb, const bf16_t* __restrict__ Kb,
    const bf16_t* __restrict__ VT, const bf16_t* __restrict__ G,
    bf16_t* __restrict__ O) {
  __shared__ bf16_t P[4][16][104];  // 104 stride: breaks LDS bank conflicts
  const int tid = threadIdx.x, w = tid >> 6, lane = tid & 63;
  const int quad = lane >> 4, t15 = lane & 15;
  const int unit = blockIdx.x * 4 + w;  // 0..2047
  const int qt = unit & 127, bh = unit >> 7;
  const int h = bh & 7, b = bh >> 3;
  const int q0 = qt * 16, tbase = q0 - 32;
  const size_t rowbase = (size_t)b * 2048;

  // Q A-fragment (K=32 = full head dim)
  bf16x8 aq = *(const bf16x8*)(Qb + (rowbase + q0 + t15) * 256 + h * 32 + quad * 8);

  const f32x4 zf = {0.f, 0.f, 0.f, 0.f};
  f32x4 sc[5];
#pragma unroll
  for (int j = 0; j < 5; ++j) {
    int t = tbase + j * 16 + t15;
    bf16x8 bk = zero_bf16x8();
    if ((unsigned)t < 2048u)
      bk = *(const bf16x8*)(Kb + (rowbase + t) * 256 + h * 32 + quad * 8);
    sc[j] = MFMA(aq, bk, zf);
  }

  const float scale = 0.17677669529663687f;  // 1/sqrt(32)
  float mx[4] = {-3.0e38f, -3.0e38f, -3.0e38f, -3.0e38f};
#pragma unroll
  for (int j = 0; j < 5; ++j) {
    int t = tbase + j * 16 + t15;
#pragma unroll
    for (int r = 0; r < 4; ++r) {
      int q = q0 + quad * 4 + r;
      int dd = q - t;
      bool valid = ((unsigned)t < 2048u) && (dd <= 32) && (dd >= -32);
      float v = valid ? sc[j][r] * scale : -1e30f;
      sc[j][r] = v;
      mx[r] = fmaxf(mx[r], v);
    }
  }
#pragma unroll
  for (int off = 1; off < 16; off <<= 1) {
#pragma unroll
    for (int r = 0; r < 4; ++r) mx[r] = fmaxf(mx[r], __shfl_xor(mx[r], off));
  }
  float sum[4] = {0.f, 0.f, 0.f, 0.f};
#pragma unroll
  for (int j = 0; j < 5; ++j) {
#pragma unroll
    for (int r = 0; r < 4; ++r) {
      float e = __expf(sc[j][r] - mx[r]);
      sc[j][r] = e;
      sum[r] += e;
    }
  }
#pragma unroll
  for (int off = 1; off < 16; off <<= 1) {
#pragma unroll
    for (int r = 0; r < 4; ++r) sum[r] += __shfl_xor(sum[r], off);
  }
  float inv[4];
#pragma unroll
  for (int r = 0; r < 4; ++r) inv[r] = 1.f / sum[r];

  // C-layout -> LDS (rows q_local, cols t_local 0..95, cols 80..95 zero pad)
#pragma unroll
  for (int j = 0; j < 5; ++j) {
#pragma unroll
    for (int r = 0; r < 4; ++r)
      P[w][quad * 4 + r][j * 16 + t15] = (bf16_t)(sc[j][r] * inv[r]);
  }
#pragma unroll
  for (int r = 0; r < 4; ++r) P[w][quad * 4 + r][80 + t15] = (bf16_t)0.f;
  __syncthreads();

  f32x4 y0 = zf, y1 = zf;
#pragma unroll
  for (int kc = 0; kc < 3; ++kc) {
    bf16x8 pa = *(const bf16x8*)&P[w][t15][kc * 32 + quad * 8];
    int ts = tbase + kc * 32 + quad * 8;  // multiple of 8: chunk fully in or out
    bf16x8 bv0 = zero_bf16x8(), bv1 = zero_bf16x8();
    if (ts >= 0 && ts + 8 <= 2048) {
      const bf16_t* vbase = VT + ((size_t)((b * 8 + h) * 32) + t15) * 2048 + ts;
      bv0 = *(const bf16x8*)vbase;
      bv1 = *(const bf16x8*)(vbase + (size_t)16 * 2048);
    }
    y0 = MFMA(pa, bv0, y0);
    y1 = MFMA(pa, bv1, y1);
  }

#pragma unroll
  for (int r = 0; r < 4; ++r) {
    int q = q0 + quad * 4 + r;
    size_t base = (rowbase + q) * 256 + h * 32;
    float g0 = (float)G[base + t15];
    float g1 = (float)G[base + 16 + t15];
    O[base + t15] = (bf16_t)(y0[r] * g0);
    O[base + 16 + t15] = (bf16_t)(y1[r] * g1);
  }
}

// ---------------------------------------------------------------------------
// Kernel 3: out = O @ OW.T + Ob, fp32 output. Same tiling as proj_kernel.
// ---------------------------------------------------------------------------
__global__ __launch_bounds__(256) void out_kernel(
    const bf16_t* __restrict__ O, const bf16_t* __restrict__ OWb,
    const float* __restrict__ Ob, float* __restrict__ out) {
  const int tid = threadIdx.x, w = tid >> 6, lane = tid & 63;
  const int quad = lane >> 4, t15 = lane & 15;
  const int m0 = blockIdx.x * 64 + w * 16;
  const int n0 = blockIdx.y * 64;

  const f32x4 zf = {0.f, 0.f, 0.f, 0.f};
  f32x4 acc[4] = {zf, zf, zf, zf};

  for (int kc = 0; kc < 8; ++kc) {
    bf16x8 a = *(const bf16x8*)(O + (size_t)(m0 + t15) * 256 + kc * 32 + quad * 8);
#pragma unroll
    for (int nf = 0; nf < 4; ++nf) {
      bf16x8 bw = *(const bf16x8*)(OWb + (size_t)(n0 + nf * 16 + t15) * 256 + kc * 32 + quad * 8);
      acc[nf] = MFMA(a, bw, acc[nf]);
    }
  }

  const int mm0 = m0 + quad * 4;
#pragma unroll
  for (int nf = 0; nf < 4; ++nf) {
    int nn = n0 + nf * 16 + t15;
    float bias = Ob[nn];
#pragma unroll
    for (int r = 0; r < 4; ++r)
      out[(size_t)(mm0 + r) * 256 + nn] = acc[nf][r] + bias;
  }
}

// ---------------------------------------------------------------------------
extern "C" void kernel_launch(void* const* d_in, const int* in_sizes, int n_in,
                              void* d_out, int out_size, void* d_ws, size_t ws_size,
                              hipStream_t stream) {
  const float* Qin = (const float*)d_in[0];
  const float* Kin = (const float*)d_in[1];
  const float* Vin = (const float*)d_in[2];
  const float* QT  = (const float*)d_in[3];
  const float* KT  = (const float*)d_in[4];
  const float* VTr = (const float*)d_in[5];
  const float* GW  = (const float*)d_in[6];
  const float* Gb  = (const float*)d_in[7];
  const float* OW  = (const float*)d_in[8];
  const float* Ob  = (const float*)d_in[9];
  float* out = (float*)d_out;

  char* ws = (char*)d_ws;
  const size_t MB = 1u << 20;
  bf16_t* Qb = (bf16_t*)(ws + 0 * MB);   // [B,S,256] bf16, 2 MB
  bf16_t* Kb = (bf16_t*)(ws + 2 * MB);   // [B,S,256] bf16, 2 MB
  bf16_t* VT = (bf16_t*)(ws + 4 * MB);   // [B,H,C,S] bf16, 2 MB
  bf16_t* G  = (bf16_t*)(ws + 6 * MB);   // [B,S,256] bf16, 2 MB
  bf16_t* O  = (bf16_t*)(ws + 8 * MB);   // [B,S,256] bf16, 2 MB
  bf16_t* Wb = (bf16_t*)(ws + 10 * MB);  // 5 x [256][256] bf16, 640 KB

  prep_weights<<<1280, 256, 0, stream>>>(QT, KT, VTr, GW, OW, Wb);
  proj_kernel<<<dim3(64, 4, 4), 256, 0, stream>>>(Qin, Kin, Vin, Wb, Gb, Qb, Kb, VT, G);
  attn_kernel<<<512, 256, 0, stream>>>(Qb, Kb, VT, G, O);
  out_kernel<<<dim3(64, 4), 256, 0, stream>>>(O, Wb + 4 * 65536, Ob, out);
}

// Round 2
// 104.310 us; speedup vs baseline: 1.1184x; 1.1184x over previous
//
#include <hip/hip_runtime.h>
#include <hip/hip_bf16.h>

typedef __bf16 bf16_t;
typedef __attribute__((ext_vector_type(8))) __bf16 bf16x8;
typedef __attribute__((ext_vector_type(4))) __bf16 bf16x4;
typedef __attribute__((ext_vector_type(4))) float f32x4;

#define MFMA(a, b, c) __builtin_amdgcn_mfma_f32_16x16x32_bf16((a), (b), (c), 0, 0, 0)

// k-dim pad: 260 => row stride 520 B (8 B aligned for ds b64, odd dword-pair
// stride => fragment ds_read_b64 conflict-free, staging writes <=4-way)
#define WK 260

static __device__ __forceinline__ bf16x8 zero_bf16x8() {
  bf16x8 z;
#pragma unroll
  for (int i = 0; i < 8; ++i) z[i] = (bf16_t)0.f;
  return z;
}

static __device__ __forceinline__ bf16x8 join8(bf16x4 lo, bf16x4 hi) {
  bf16x8 r;
  r[0] = lo[0]; r[1] = lo[1]; r[2] = lo[2]; r[3] = lo[3];
  r[4] = hi[0]; r[5] = hi[1]; r[6] = hi[2]; r[7] = hi[3];
  return r;
}

static __device__ __forceinline__ bf16x8 cvt8(float4 a, float4 b) {
  bf16x8 r;
  r[0] = (bf16_t)a.x; r[1] = (bf16_t)a.y; r[2] = (bf16_t)a.z; r[3] = (bf16_t)a.w;
  r[4] = (bf16_t)b.x; r[5] = (bf16_t)b.y; r[6] = (bf16_t)b.z; r[7] = (bf16_t)b.w;
  return r;
}

// ---------------------------------------------------------------------------
// Kernel 1: projections with in-block weight transpose to LDS.
// grid (Mtiles=64, Ntiles=4, job=4), 256 thr = 4 waves, wave = 16(m)x64(n).
// job 0: Q=Qin@QTrans -> Qb bf16 [B,S,256]
// job 1: K=Kin@KTrans -> Kb bf16 [B,S,256]
// job 2: V=Vin@VTrans -> VT bf16 [B,H,C,S] (transposed for PV B-fragments)
// job 3: G=sigmoid(Vin@GW.T+Gb) -> G bf16 [B,S,256]
// Wl[n_local][k] bf16: B-fragment needs k-contiguous per lane.
// ---------------------------------------------------------------------------
__global__ __launch_bounds__(256) void proj_kernel(
    const float* __restrict__ Qin, const float* __restrict__ Kin,
    const float* __restrict__ Vin, const float* __restrict__ QT,
    const float* __restrict__ KT, const float* __restrict__ VTr,
    const float* __restrict__ GW, const float* __restrict__ Gb,
    bf16_t* __restrict__ Qb, bf16_t* __restrict__ Kb,
    bf16_t* __restrict__ VT, bf16_t* __restrict__ G) {
  __shared__ bf16_t Wl[64][WK];
  const int tid = threadIdx.x, w = tid >> 6, lane = tid & 63;
  const int quad = lane >> 4, t15 = lane & 15;
  const int job = blockIdx.z;
  const int m0 = blockIdx.x * 64 + w * 16;
  const int n0 = blockIdx.y * 64;
  const float* A = (job == 0) ? Qin : (job == 1) ? Kin : Vin;

  // --- stage weight tile [k=0..255][n=n0..n0+63] into Wl[n][k] (bf16) ---
  if (job < 3) {
    // src is [k=256][n=256]; transpose. Thread: 16 iters x 4 k-values, 1 n.
    const float* src = (job == 0) ? QT : (job == 1) ? KT : VTr;
    const int nl = tid & 63;           // coalesced along n
    const int kq = (tid >> 6) * 4;
#pragma unroll
    for (int i = 0; i < 16; ++i) {
      int k0 = i * 16 + kq;
      float f0 = src[(size_t)(k0 + 0) * 256 + n0 + nl];
      float f1 = src[(size_t)(k0 + 1) * 256 + n0 + nl];
      float f2 = src[(size_t)(k0 + 2) * 256 + n0 + nl];
      float f3 = src[(size_t)(k0 + 3) * 256 + n0 + nl];
      bf16x4 w4;
      w4[0] = (bf16_t)f0; w4[1] = (bf16_t)f1; w4[2] = (bf16_t)f2; w4[3] = (bf16_t)f3;
      *(bf16x4*)&Wl[nl][k0] = w4;      // ds_write_b64, ~4-way conflict
    }
  } else {
    // GW is [n=256][k=256] (nn.Linear [out,in]); straight cast.
    const int kk = (tid & 63) * 4;
    const int nw = tid >> 6;
#pragma unroll
    for (int i = 0; i < 16; ++i) {
      int n = i * 4 + nw;
      float4 v = *(const float4*)(GW + (size_t)(n0 + n) * 256 + kk);
      bf16x4 w4;
      w4[0] = (bf16_t)v.x; w4[1] = (bf16_t)v.y; w4[2] = (bf16_t)v.z; w4[3] = (bf16_t)v.w;
      *(bf16x4*)&Wl[n][kk] = w4;
    }
  }
  __syncthreads();

  const f32x4 zf = {0.f, 0.f, 0.f, 0.f};
  f32x4 acc[4] = {zf, zf, zf, zf};

  for (int kc = 0; kc < 8; ++kc) {
    const float* ap = A + (size_t)(m0 + t15) * 256 + kc * 32 + quad * 8;
    float4 x0 = *(const float4*)ap;
    float4 x1 = *(const float4*)(ap + 4);
    bf16x8 a = cvt8(x0, x1);
#pragma unroll
    for (int nf = 0; nf < 4; ++nf) {
      bf16x4 lo = *(const bf16x4*)&Wl[nf * 16 + t15][kc * 32 + quad * 8];
      bf16x4 hi = *(const bf16x4*)&Wl[nf * 16 + t15][kc * 32 + quad * 8 + 4];
      acc[nf] = MFMA(a, join8(lo, hi), acc[nf]);
    }
  }

  const int mm0 = m0 + quad * 4;  // 4 consecutive output rows (r=0..3)
  if (job == 2) {
    const int b = mm0 >> 11;
    const int s = mm0 & 2047;
#pragma unroll
    for (int nf = 0; nf < 4; ++nf) {
      int nn = n0 + nf * 16 + t15;
      int h = nn >> 5, c = nn & 31;
      bf16x4 v4;
#pragma unroll
      for (int r = 0; r < 4; ++r) v4[r] = (bf16_t)acc[nf][r];
      *(bf16x4*)(VT + (size_t)((b * 8 + h) * 32 + c) * 2048 + s) = v4;
    }
  } else if (job == 3) {
#pragma unroll
    for (int nf = 0; nf < 4; ++nf) {
      int nn = n0 + nf * 16 + t15;
      float bias = Gb[nn];
#pragma unroll
      for (int r = 0; r < 4; ++r) {
        float g = 1.f / (1.f + __expf(-(acc[nf][r] + bias)));
        G[(size_t)(mm0 + r) * 256 + nn] = (bf16_t)g;
      }
    }
  } else {
    bf16_t* dst = (job == 0) ? Qb : Kb;
#pragma unroll
    for (int nf = 0; nf < 4; ++nf) {
      int nn = n0 + nf * 16 + t15;
#pragma unroll
      for (int r = 0; r < 4; ++r)
        dst[(size_t)(mm0 + r) * 256 + nn] = (bf16_t)acc[nf][r];
    }
  }
}

// ---------------------------------------------------------------------------
// Kernel 2: fused windowed attention + gating + output projection.
// 512 threads = 8 waves; wave h handles head h of one 16-query tile.
// Scores (5 MFMAs over [q0-32,q0+47]) -> fp32 softmax -> P via LDS -> PV
// (6 MFMAs) -> gate -> gathered O tile in LDS -> barrier ->
// out = O @ OW^T + Ob (wave h computes n-slice [h*32, h*32+32)).
// grid = B*S/16 = 256 blocks.
// ---------------------------------------------------------------------------
__global__ __launch_bounds__(512) void attn_out_kernel(
    const bf16_t* __restrict__ Qb, const bf16_t* __restrict__ Kb,
    const bf16_t* __restrict__ VT, const bf16_t* __restrict__ G,
    const float* __restrict__ OW, const float* __restrict__ Ob,
    float* __restrict__ out) {
  __shared__ bf16_t P[8][16][104];  // per-wave P tile (C->A layout transform)
  __shared__ bf16_t Ol[16][WK];     // gated attention output tile, [q_local][k]
  const int tid = threadIdx.x, h = tid >> 6, lane = tid & 63;
  const int quad = lane >> 4, t15 = lane & 15;
  const int qt = blockIdx.x & 127, b = blockIdx.x >> 7;
  const int q0 = qt * 16, tbase = q0 - 32;
  const size_t rowbase = (size_t)b * 2048;

  // Q A-fragment (K=32 = full head dim)
  bf16x8 aq = *(const bf16x8*)(Qb + (rowbase + q0 + t15) * 256 + h * 32 + quad * 8);

  const f32x4 zf = {0.f, 0.f, 0.f, 0.f};
  f32x4 sc[5];
#pragma unroll
  for (int j = 0; j < 5; ++j) {
    int t = tbase + j * 16 + t15;
    bf16x8 bk = zero_bf16x8();
    if ((unsigned)t < 2048u)
      bk = *(const bf16x8*)(Kb + (rowbase + t) * 256 + h * 32 + quad * 8);
    sc[j] = MFMA(aq, bk, zf);
  }

  const float scale = 0.17677669529663687f;  // 1/sqrt(32)
  float mx[4] = {-3.0e38f, -3.0e38f, -3.0e38f, -3.0e38f};
#pragma unroll
  for (int j = 0; j < 5; ++j) {
    int t = tbase + j * 16 + t15;
#pragma unroll
    for (int r = 0; r < 4; ++r) {
      int q = q0 + quad * 4 + r;
      int dd = q - t;
      bool valid = ((unsigned)t < 2048u) && (dd <= 32) && (dd >= -32);
      float v = valid ? sc[j][r] * scale : -1e30f;
      sc[j][r] = v;
      mx[r] = fmaxf(mx[r], v);
    }
  }
#pragma unroll
  for (int off = 1; off < 16; off <<= 1) {
#pragma unroll
    for (int r = 0; r < 4; ++r) mx[r] = fmaxf(mx[r], __shfl_xor(mx[r], off));
  }
  float sum[4] = {0.f, 0.f, 0.f, 0.f};
#pragma unroll
  for (int j = 0; j < 5; ++j) {
#pragma unroll
    for (int r = 0; r < 4; ++r) {
      float e = __expf(sc[j][r] - mx[r]);
      sc[j][r] = e;
      sum[r] += e;
    }
  }
#pragma unroll
  for (int off = 1; off < 16; off <<= 1) {
#pragma unroll
    for (int r = 0; r < 4; ++r) sum[r] += __shfl_xor(sum[r], off);
  }
  float inv[4];
#pragma unroll
  for (int r = 0; r < 4; ++r) inv[r] = 1.f / sum[r];

  // C-layout -> LDS rows q_local, cols t_local (80..95 zero pad)
#pragma unroll
  for (int j = 0; j < 5; ++j) {
#pragma unroll
    for (int r = 0; r < 4; ++r)
      P[h][quad * 4 + r][j * 16 + t15] = (bf16_t)(sc[j][r] * inv[r]);
  }
#pragma unroll
  for (int r = 0; r < 4; ++r) P[h][quad * 4 + r][80 + t15] = (bf16_t)0.f;
  __syncthreads();

  f32x4 y0 = zf, y1 = zf;
#pragma unroll
  for (int kc = 0; kc < 3; ++kc) {
    bf16x8 pa = *(const bf16x8*)&P[h][t15][kc * 32 + quad * 8];
    int ts = tbase + kc * 32 + quad * 8;  // multiple of 8: chunk fully in/out
    bf16x8 bv0 = zero_bf16x8(), bv1 = zero_bf16x8();
    if (ts >= 0 && ts + 8 <= 2048) {
      const bf16_t* vbase = VT + ((size_t)((b * 8 + h) * 32) + t15) * 2048 + ts;
      bv0 = *(const bf16x8*)vbase;
      bv1 = *(const bf16x8*)(vbase + (size_t)16 * 2048);
    }
    y0 = MFMA(pa, bv0, y0);
    y1 = MFMA(pa, bv1, y1);
  }

  // gate and gather the 16x256 O tile into LDS
#pragma unroll
  for (int r = 0; r < 4; ++r) {
    int q = q0 + quad * 4 + r;
    size_t base = (rowbase + q) * 256 + h * 32;
    float g0 = (float)G[base + t15];
    float g1 = (float)G[base + 16 + t15];
    Ol[quad * 4 + r][h * 32 + t15] = (bf16_t)(y0[r] * g0);
    Ol[quad * 4 + r][h * 32 + 16 + t15] = (bf16_t)(y1[r] * g1);
  }
  __syncthreads();

  // out-projection: wave h computes out[:, h*32 .. h*32+32)
  f32x4 acc[2] = {zf, zf};
  for (int kc = 0; kc < 8; ++kc) {
    bf16x4 alo = *(const bf16x4*)&Ol[t15][kc * 32 + quad * 8];
    bf16x4 ahi = *(const bf16x4*)&Ol[t15][kc * 32 + quad * 8 + 4];
    bf16x8 a = join8(alo, ahi);
#pragma unroll
    for (int nf = 0; nf < 2; ++nf) {
      int n = h * 32 + nf * 16 + t15;
      const float* wp = OW + (size_t)n * 256 + kc * 32 + quad * 8;
      float4 w0 = *(const float4*)wp;
      float4 w1 = *(const float4*)(wp + 4);
      acc[nf] = MFMA(a, cvt8(w0, w1), acc[nf]);
    }
  }
#pragma unroll
  for (int nf = 0; nf < 2; ++nf) {
    int n = h * 32 + nf * 16 + t15;
    float bias = Ob[n];
#pragma unroll
    for (int r = 0; r < 4; ++r)
      out[(rowbase + q0 + quad * 4 + r) * 256 + n] = acc[nf][r] + bias;
  }
}

// ---------------------------------------------------------------------------
extern "C" void kernel_launch(void* const* d_in, const int* in_sizes, int n_in,
                              void* d_out, int out_size, void* d_ws, size_t ws_size,
                              hipStream_t stream) {
  const float* Qin = (const float*)d_in[0];
  const float* Kin = (const float*)d_in[1];
  const float* Vin = (const float*)d_in[2];
  const float* QT  = (const float*)d_in[3];
  const float* KT  = (const float*)d_in[4];
  const float* VTr = (const float*)d_in[5];
  const float* GW  = (const float*)d_in[6];
  const float* Gb  = (const float*)d_in[7];
  const float* OW  = (const float*)d_in[8];
  const float* Ob  = (const float*)d_in[9];
  float* out = (float*)d_out;

  char* ws = (char*)d_ws;
  const size_t MB = 1u << 20;
  bf16_t* Qb = (bf16_t*)(ws + 0 * MB);   // [B,S,256] bf16, 2 MB
  bf16_t* Kb = (bf16_t*)(ws + 2 * MB);   // [B,S,256] bf16, 2 MB
  bf16_t* VT = (bf16_t*)(ws + 4 * MB);   // [B,H,C,S] bf16, 2 MB
  bf16_t* G  = (bf16_t*)(ws + 6 * MB);   // [B,S,256] bf16, 2 MB

  proj_kernel<<<dim3(64, 4, 4), 256, 0, stream>>>(Qin, Kin, Vin, QT, KT, VTr,
                                                  GW, Gb, Qb, Kb, VT, G);
  attn_out_kernel<<<256, 512, 0, stream>>>(Qb, Kb, VT, G, OW, Ob, out);
}

// Round 3
// 103.648 us; speedup vs baseline: 1.1256x; 1.0064x over previous
//
#include <hip/hip_runtime.h>
#include <hip/hip_bf16.h>

typedef __bf16 bf16_t;
typedef __attribute__((ext_vector_type(8))) __bf16 bf16x8;
typedef __attribute__((ext_vector_type(4))) __bf16 bf16x4;
typedef __attribute__((ext_vector_type(4))) float f32x4;

#define MFMA(a, b, c) __builtin_amdgcn_mfma_f32_16x16x32_bf16((a), (b), (c), 0, 0, 0)

// k-dim pad: 260 => row stride 520 B (8 B aligned for ds b64, odd dword-pair
// stride => fragment ds_read_b64 conflict-free, staging writes <=4-way)
#define WK 260

static __device__ __forceinline__ bf16x8 zero_bf16x8() {
  bf16x8 z;
#pragma unroll
  for (int i = 0; i < 8; ++i) z[i] = (bf16_t)0.f;
  return z;
}

static __device__ __forceinline__ bf16x8 join8(bf16x4 lo, bf16x4 hi) {
  bf16x8 r;
  r[0] = lo[0]; r[1] = lo[1]; r[2] = lo[2]; r[3] = lo[3];
  r[4] = hi[0]; r[5] = hi[1]; r[6] = hi[2]; r[7] = hi[3];
  return r;
}

static __device__ __forceinline__ bf16x8 cvt8(float4 a, float4 b) {
  bf16x8 r;
  r[0] = (bf16_t)a.x; r[1] = (bf16_t)a.y; r[2] = (bf16_t)a.z; r[3] = (bf16_t)a.w;
  r[4] = (bf16_t)b.x; r[5] = (bf16_t)b.y; r[6] = (bf16_t)b.z; r[7] = (bf16_t)b.w;
  return r;
}

// ---------------------------------------------------------------------------
// Kernel 1: projections with in-block weight transpose to LDS.
// grid (Mtiles=32, Ntiles=4, job=4), 256 thr = 4 waves.
// Each block: m=128 rows x n=64 cols; wave w covers m-subtiles {w*16, w*16+64}
// (2 A-fragments, 8 MFMA-accs) -> weight tile staged once per 128 m-rows
// (half the L2 restaging traffic of the m=64 version).
// job 0: Q=Qin@QTrans -> Qb bf16 [B,S,256]
// job 1: K=Kin@KTrans -> Kb bf16 [B,S,256]
// job 2: V=Vin@VTrans -> VT bf16 [B,H,C,S] (transposed for PV B-fragments)
// job 3: G=sigmoid(Vin@GW.T+Gb) -> G bf16 [B,S,256]
// ---------------------------------------------------------------------------
__global__ __launch_bounds__(256) void proj_kernel(
    const float* __restrict__ Qin, const float* __restrict__ Kin,
    const float* __restrict__ Vin, const float* __restrict__ QT,
    const float* __restrict__ KT, const float* __restrict__ VTr,
    const float* __restrict__ GW, const float* __restrict__ Gb,
    bf16_t* __restrict__ Qb, bf16_t* __restrict__ Kb,
    bf16_t* __restrict__ VT, bf16_t* __restrict__ G) {
  __shared__ bf16_t Wl[64][WK];
  const int tid = threadIdx.x, w = tid >> 6, lane = tid & 63;
  const int quad = lane >> 4, t15 = lane & 15;
  const int job = blockIdx.z;
  const int m0 = blockIdx.x * 128 + w * 16;
  const int n0 = blockIdx.y * 64;
  const float* A = (job == 0) ? Qin : (job == 1) ? Kin : Vin;

  // --- stage weight tile [k=0..255][n=n0..n0+63] into Wl[n][k] (bf16) ---
  if (job < 3) {
    // src is [k=256][n=256]; transpose. Thread: 16 iters x 4 k-values, 1 n.
    const float* src = (job == 0) ? QT : (job == 1) ? KT : VTr;
    const int nl = tid & 63;           // coalesced along n
    const int kq = (tid >> 6) * 4;
#pragma unroll
    for (int i = 0; i < 16; ++i) {
      int k0 = i * 16 + kq;
      float f0 = src[(size_t)(k0 + 0) * 256 + n0 + nl];
      float f1 = src[(size_t)(k0 + 1) * 256 + n0 + nl];
      float f2 = src[(size_t)(k0 + 2) * 256 + n0 + nl];
      float f3 = src[(size_t)(k0 + 3) * 256 + n0 + nl];
      bf16x4 w4;
      w4[0] = (bf16_t)f0; w4[1] = (bf16_t)f1; w4[2] = (bf16_t)f2; w4[3] = (bf16_t)f3;
      *(bf16x4*)&Wl[nl][k0] = w4;      // ds_write_b64, ~4-way conflict
    }
  } else {
    // GW is [n=256][k=256] (nn.Linear [out,in]); straight cast.
    const int kk = (tid & 63) * 4;
    const int nw = tid >> 6;
#pragma unroll
    for (int i = 0; i < 16; ++i) {
      int n = i * 4 + nw;
      float4 v = *(const float4*)(GW + (size_t)(n0 + n) * 256 + kk);
      bf16x4 w4;
      w4[0] = (bf16_t)v.x; w4[1] = (bf16_t)v.y; w4[2] = (bf16_t)v.z; w4[3] = (bf16_t)v.w;
      *(bf16x4*)&Wl[n][kk] = w4;
    }
  }
  __syncthreads();

  const f32x4 zf = {0.f, 0.f, 0.f, 0.f};
  f32x4 acc[2][4] = {{zf, zf, zf, zf}, {zf, zf, zf, zf}};

  for (int kc = 0; kc < 8; ++kc) {
    bf16x8 a[2];
#pragma unroll
    for (int mi = 0; mi < 2; ++mi) {
      const float* ap = A + (size_t)(m0 + mi * 64 + t15) * 256 + kc * 32 + quad * 8;
      float4 x0 = *(const float4*)ap;
      float4 x1 = *(const float4*)(ap + 4);
      a[mi] = cvt8(x0, x1);
    }
#pragma unroll
    for (int nf = 0; nf < 4; ++nf) {
      bf16x4 lo = *(const bf16x4*)&Wl[nf * 16 + t15][kc * 32 + quad * 8];
      bf16x4 hi = *(const bf16x4*)&Wl[nf * 16 + t15][kc * 32 + quad * 8 + 4];
      bf16x8 bw = join8(lo, hi);
#pragma unroll
      for (int mi = 0; mi < 2; ++mi) acc[mi][nf] = MFMA(a[mi], bw, acc[mi][nf]);
    }
  }

#pragma unroll
  for (int mi = 0; mi < 2; ++mi) {
    const int mm0 = m0 + mi * 64 + quad * 4;  // 4 consecutive output rows
    if (job == 2) {
      const int b = mm0 >> 11;
      const int s = mm0 & 2047;
#pragma unroll
      for (int nf = 0; nf < 4; ++nf) {
        int nn = n0 + nf * 16 + t15;
        int h = nn >> 5, c = nn & 31;
        bf16x4 v4;
#pragma unroll
        for (int r = 0; r < 4; ++r) v4[r] = (bf16_t)acc[mi][nf][r];
        *(bf16x4*)(VT + (size_t)((b * 8 + h) * 32 + c) * 2048 + s) = v4;
      }
    } else if (job == 3) {
#pragma unroll
      for (int nf = 0; nf < 4; ++nf) {
        int nn = n0 + nf * 16 + t15;
        float bias = Gb[nn];
#pragma unroll
        for (int r = 0; r < 4; ++r) {
          float g = 1.f / (1.f + __expf(-(acc[mi][nf][r] + bias)));
          G[(size_t)(mm0 + r) * 256 + nn] = (bf16_t)g;
        }
      }
    } else {
      bf16_t* dst = (job == 0) ? Qb : Kb;
#pragma unroll
      for (int nf = 0; nf < 4; ++nf) {
        int nn = n0 + nf * 16 + t15;
#pragma unroll
        for (int r = 0; r < 4; ++r)
          dst[(size_t)(mm0 + r) * 256 + nn] = (bf16_t)acc[mi][nf][r];
      }
    }
  }
}

// ---------------------------------------------------------------------------
// Kernel 2: fused windowed attention + gating + output projection.
// 512 threads = 8 waves; wave h handles head h of one 16-query tile.
// Scores (5 MFMAs over [q0-32,q0+47]) -> fp32 softmax -> P via LDS -> PV
// (6 MFMAs) -> gate -> gathered O tile in LDS -> barrier ->
// out = O @ OW^T + Ob (wave h computes n-slice [h*32, h*32+32)).
// grid = B*S/16 = 256 blocks. G gate values prefetched before the score
// phase so their latency hides under QK^T + softmax.
// ---------------------------------------------------------------------------
__global__ __launch_bounds__(512) void attn_out_kernel(
    const bf16_t* __restrict__ Qb, const bf16_t* __restrict__ Kb,
    const bf16_t* __restrict__ VT, const bf16_t* __restrict__ G,
    const float* __restrict__ OW, const float* __restrict__ Ob,
    float* __restrict__ out) {
  __shared__ bf16_t P[8][16][104];  // per-wave P tile (C->A layout transform)
  __shared__ bf16_t Ol[16][WK];     // gated attention output tile, [q_local][k]
  const int tid = threadIdx.x, h = tid >> 6, lane = tid & 63;
  const int quad = lane >> 4, t15 = lane & 15;
  const int qt = blockIdx.x & 127, b = blockIdx.x >> 7;
  const int q0 = qt * 16, tbase = q0 - 32;
  const size_t rowbase = (size_t)b * 2048;

  // Q A-fragment (K=32 = full head dim)
  bf16x8 aq = *(const bf16x8*)(Qb + (rowbase + q0 + t15) * 256 + h * 32 + quad * 8);

  // prefetch gate values (used only after PV) — hides G latency under scores
  float g0[4], g1[4];
#pragma unroll
  for (int r = 0; r < 4; ++r) {
    size_t base = (rowbase + q0 + quad * 4 + r) * 256 + h * 32;
    g0[r] = (float)G[base + t15];
    g1[r] = (float)G[base + 16 + t15];
  }
  const float ob0 = Ob[h * 32 + t15];
  const float ob1 = Ob[h * 32 + 16 + t15];

  const f32x4 zf = {0.f, 0.f, 0.f, 0.f};
  f32x4 sc[5];
#pragma unroll
  for (int j = 0; j < 5; ++j) {
    int t = tbase + j * 16 + t15;
    bf16x8 bk = zero_bf16x8();
    if ((unsigned)t < 2048u)
      bk = *(const bf16x8*)(Kb + (rowbase + t) * 256 + h * 32 + quad * 8);
    sc[j] = MFMA(aq, bk, zf);
  }

  const float scale = 0.17677669529663687f;  // 1/sqrt(32)
  float mx[4] = {-3.0e38f, -3.0e38f, -3.0e38f, -3.0e38f};
#pragma unroll
  for (int j = 0; j < 5; ++j) {
    int t = tbase + j * 16 + t15;
#pragma unroll
    for (int r = 0; r < 4; ++r) {
      int q = q0 + quad * 4 + r;
      int dd = q - t;
      bool valid = ((unsigned)t < 2048u) && (dd <= 32) && (dd >= -32);
      float v = valid ? sc[j][r] * scale : -1e30f;
      sc[j][r] = v;
      mx[r] = fmaxf(mx[r], v);
    }
  }
#pragma unroll
  for (int off = 1; off < 16; off <<= 1) {
#pragma unroll
    for (int r = 0; r < 4; ++r) mx[r] = fmaxf(mx[r], __shfl_xor(mx[r], off));
  }
  float sum[4] = {0.f, 0.f, 0.f, 0.f};
#pragma unroll
  for (int j = 0; j < 5; ++j) {
#pragma unroll
    for (int r = 0; r < 4; ++r) {
      float e = __expf(sc[j][r] - mx[r]);
      sc[j][r] = e;
      sum[r] += e;
    }
  }
#pragma unroll
  for (int off = 1; off < 16; off <<= 1) {
#pragma unroll
    for (int r = 0; r < 4; ++r) sum[r] += __shfl_xor(sum[r], off);
  }
  float inv[4];
#pragma unroll
  for (int r = 0; r < 4; ++r) inv[r] = 1.f / sum[r];

  // C-layout -> LDS rows q_local, cols t_local (80..95 zero pad)
#pragma unroll
  for (int j = 0; j < 5; ++j) {
#pragma unroll
    for (int r = 0; r < 4; ++r)
      P[h][quad * 4 + r][j * 16 + t15] = (bf16_t)(sc[j][r] * inv[r]);
  }
#pragma unroll
  for (int r = 0; r < 4; ++r) P[h][quad * 4 + r][80 + t15] = (bf16_t)0.f;
  __syncthreads();

  f32x4 y0 = zf, y1 = zf;
#pragma unroll
  for (int kc = 0; kc < 3; ++kc) {
    bf16x8 pa = *(const bf16x8*)&P[h][t15][kc * 32 + quad * 8];
    int ts = tbase + kc * 32 + quad * 8;  // multiple of 8: chunk fully in/out
    bf16x8 bv0 = zero_bf16x8(), bv1 = zero_bf16x8();
    if (ts >= 0 && ts + 8 <= 2048) {
      const bf16_t* vbase = VT + ((size_t)((b * 8 + h) * 32) + t15) * 2048 + ts;
      bv0 = *(const bf16x8*)vbase;
      bv1 = *(const bf16x8*)(vbase + (size_t)16 * 2048);
    }
    y0 = MFMA(pa, bv0, y0);
    y1 = MFMA(pa, bv1, y1);
  }

  // gate and gather the 16x256 O tile into LDS
#pragma unroll
  for (int r = 0; r < 4; ++r) {
    Ol[quad * 4 + r][h * 32 + t15] = (bf16_t)(y0[r] * g0[r]);
    Ol[quad * 4 + r][h * 32 + 16 + t15] = (bf16_t)(y1[r] * g1[r]);
  }
  __syncthreads();

  // out-projection: wave h computes out[:, h*32 .. h*32+32)
  f32x4 acc[2] = {zf, zf};
  for (int kc = 0; kc < 8; ++kc) {
    bf16x4 alo = *(const bf16x4*)&Ol[t15][kc * 32 + quad * 8];
    bf16x4 ahi = *(const bf16x4*)&Ol[t15][kc * 32 + quad * 8 + 4];
    bf16x8 a = join8(alo, ahi);
#pragma unroll
    for (int nf = 0; nf < 2; ++nf) {
      int n = h * 32 + nf * 16 + t15;
      const float* wp = OW + (size_t)n * 256 + kc * 32 + quad * 8;
      float4 w0 = *(const float4*)wp;
      float4 w1 = *(const float4*)(wp + 4);
      acc[nf] = MFMA(a, cvt8(w0, w1), acc[nf]);
    }
  }
#pragma unroll
  for (int nf = 0; nf < 2; ++nf) {
    int n = h * 32 + nf * 16 + t15;
    float bias = (nf == 0) ? ob0 : ob1;
#pragma unroll
    for (int r = 0; r < 4; ++r)
      out[(rowbase + q0 + quad * 4 + r) * 256 + n] = acc[nf][r] + bias;
  }
}

// ---------------------------------------------------------------------------
extern "C" void kernel_launch(void* const* d_in, const int* in_sizes, int n_in,
                              void* d_out, int out_size, void* d_ws, size_t ws_size,
                              hipStream_t stream) {
  const float* Qin = (const float*)d_in[0];
  const float* Kin = (const float*)d_in[1];
  const float* Vin = (const float*)d_in[2];
  const float* QT  = (const float*)d_in[3];
  const float* KT  = (const float*)d_in[4];
  const float* VTr = (const float*)d_in[5];
  const float* GW  = (const float*)d_in[6];
  const float* Gb  = (const float*)d_in[7];
  const float* OW  = (const float*)d_in[8];
  const float* Ob  = (const float*)d_in[9];
  float* out = (float*)d_out;

  char* ws = (char*)d_ws;
  const size_t MB = 1u << 20;
  bf16_t* Qb = (bf16_t*)(ws + 0 * MB);   // [B,S,256] bf16, 2 MB
  bf16_t* Kb = (bf16_t*)(ws + 2 * MB);   // [B,S,256] bf16, 2 MB
  bf16_t* VT = (bf16_t*)(ws + 4 * MB);   // [B,H,C,S] bf16, 2 MB
  bf16_t* G  = (bf16_t*)(ws + 6 * MB);   // [B,S,256] bf16, 2 MB

  proj_kernel<<<dim3(32, 4, 4), 256, 0, stream>>>(Qin, Kin, Vin, QT, KT, VTr,
                                                  GW, Gb, Qb, Kb, VT, G);
  attn_out_kernel<<<256, 512, 0, stream>>>(Qb, Kb, VT, G, OW, Ob, out);
}